// Round 1
// baseline (527.277 us; speedup 1.0000x reference)
//
#include <hip/hip_runtime.h>

// local_rel_trafo: out[b,n,m,i] = sum_{j,k} GP[i,j,k] * (REV[j]*T[b,n,j]) * T[b,m,k]
// B=2, N=2048, 16 PGA blade components. Output 537 MB fp32 -> HBM-write-bound.

namespace {

struct GPTab {
    signed char out[16][16];  // output blade index for (j,k), undefined if sgn==0
    signed char sgn[16][16];  // +-1 with REV(j) folded in; 0 if e0*e0 annihilates
};

// Mirrors the Python _gp_basis()/_reverse_signs() bit-twiddling exactly.
constexpr GPTab make_tab() {
    GPTab t{};
    // blades sorted by (grade, bitmask); bit0 = e0 (degenerate)
    int blade[16] = {0, 1, 2, 4, 8, 3, 5, 6, 9, 10, 12, 7, 11, 13, 14, 15};
    int idx[16] = {};
    for (int i = 0; i < 16; ++i) idx[blade[i]] = i;
    // reverse sign (-1)^(g(g-1)/2): grades 2,3 flip
    int revs[16] = {1, 1, 1, 1, 1, -1, -1, -1, -1, -1, -1, -1, -1, -1, -1, 1};
    for (int j = 0; j < 16; ++j) {
        for (int k = 0; k < 16; ++k) {
            int a = blade[j], b = blade[k];
            if (a & b & 1) { t.out[j][k] = 0; t.sgn[j][k] = 0; continue; }
            int s = 0;
            int tt = a >> 1;  // Dorst canonical-reordering sign
            while (tt) {
                int x = tt & b;
                while (x) { s += x & 1; x >>= 1; }
                tt >>= 1;
            }
            t.out[j][k] = (signed char)idx[a ^ b];
            t.sgn[j][k] = (signed char)(((s & 1) ? -1 : 1) * revs[j]);
        }
    }
    return t;
}

constexpr GPTab TAB = make_tab();

constexpr int N_RES = 2048;          // N*N = 2^22

} // namespace

__global__ __launch_bounds__(256) void grt_pairs_kernel(
        const float* __restrict__ T, float* __restrict__ out) {
    const int tid = threadIdx.x;
    const long long pbase = (long long)blockIdx.x * 256;  // first pair of block
    const int b = (int)(pbase >> 22);
    const int n = (int)((pbase >> 11) & (N_RES - 1));     // block-uniform
    const int m = (int)(pbase & (N_RES - 1)) + tid;       // 2048 % 256 == 0

    const float4* Tn4 = reinterpret_cast<const float4*>(T + ((size_t)(b * N_RES + n) << 4));
    const float4* Tm4 = reinterpret_cast<const float4*>(T + ((size_t)(b * N_RES + m) << 4));

    float a[16], c[16];
#pragma unroll
    for (int q = 0; q < 4; ++q) {
        float4 va = Tn4[q];   // uniform across block -> scalar loads
        float4 vc = Tm4[q];
        a[4 * q + 0] = va.x; a[4 * q + 1] = va.y; a[4 * q + 2] = va.z; a[4 * q + 3] = va.w;
        c[4 * q + 0] = vc.x; c[4 * q + 1] = vc.y; c[4 * q + 2] = vc.z; c[4 * q + 3] = vc.w;
    }

    float acc[16];
#pragma unroll
    for (int i = 0; i < 16; ++i) acc[i] = 0.0f;

    // 192 constant-folded FMAs (REV already folded into TAB.sgn)
#pragma unroll
    for (int j = 0; j < 16; ++j) {
#pragma unroll
        for (int k = 0; k < 16; ++k) {
            if (TAB.sgn[j][k] == 0) continue;          // folds at compile time
            const int i = TAB.out[j][k];
            if (TAB.sgn[j][k] > 0) acc[i] = fmaf( a[j], c[k], acc[i]);
            else                   acc[i] = fmaf(-a[j], c[k], acc[i]);
        }
    }

    // LDS transpose: row stride 20 floats = 80 B (16B-aligned, bank-uniform both
    // phases: 8 words/bank) -> perfectly coalesced 1 KiB/instruction global stores.
    __shared__ float lds[256 * 20];
#pragma unroll
    for (int q = 0; q < 4; ++q) {
        *reinterpret_cast<float4*>(&lds[tid * 20 + q * 4]) =
            make_float4(acc[4 * q + 0], acc[4 * q + 1], acc[4 * q + 2], acc[4 * q + 3]);
    }
    __syncthreads();

    float* outb = out + (size_t)pbase * 16;   // 4096 contiguous floats per block
#pragma unroll
    for (int it = 0; it < 4; ++it) {
        const int w  = it * 1024 + tid * 4;   // word offset in block's out chunk
        const int pp = w >> 4;                // pair-in-block
        const int jj = w & 15;                // component
        *reinterpret_cast<float4*>(&outb[w]) =
            *reinterpret_cast<const float4*>(&lds[pp * 20 + jj]);
    }
}

extern "C" void kernel_launch(void* const* d_in, const int* in_sizes, int n_in,
                              void* d_out, int out_size, void* d_ws, size_t ws_size,
                              hipStream_t stream) {
    const float* T = (const float*)d_in[0];
    float* out = (float*)d_out;
    const int blocks = out_size / (256 * 16);  // B*N*N / 256 = 32768
    grt_pairs_kernel<<<blocks, 256, 0, stream>>>(T, out);
}